// Round 8
// baseline (29.871 us; speedup 1.0000x reference)
//
#include <hip/hip_runtime.h>

// ROI max-pooling, faithful to the reference (including the buggy min/max
// ordering). feat: [B=4, C=64, H=128, W=128] f32; boxes: [B, N=64, 7] f32
// out: [B, N, C, 7, 7] f32
//
// Round-8: identical per-box body to round 7 (exact-trip flat row walk,
// buf[8] ring, scalar bin state machine, XCD channel-slicing), but the grid
// is capped at 2048 blocks (guide G11): each block grid-strides over 4 boxes
// (bn = blockIdx.y + 64*i). All blocks co-resident in one dispatch round ->
// no queuing; per-block duration = sum of 4 boxes -> tail variance halves.

constexpr int Bb = 4, Cc = 64, Hh = 128, Ww = 128, Nn = 64, BOX_DIM = 7;
constexpr int POOL = 7;
constexpr int WAVES = 2;            // channels per block
constexpr int PITCH = Ww + 1;       // 129: breaks power-of-2 bank stride
constexpr int BN_PER = 4;           // boxes per block (grid-stride)

__global__ __launch_bounds__(128) void roi_pool_kernel(
    const float* __restrict__ feat,
    const float* __restrict__ boxes,
    float* __restrict__ out)
{
    __shared__ float colmax[WAVES][POOL][PITCH];   // 7224 B

    const int wave = threadIdx.x >> 6;
    const int lane = threadIdx.x & 63;
    const int c    = blockIdx.x * WAVES + wave;    // channel (x-dim -> XCD slice)

    for (int i = 0; i < BN_PER; ++i) {
        const int bn = blockIdx.y + 64 * i;        // box index (B*N), strided
        const int b  = bn >> 6;                    // Nn = 64

        // --- box decode (same address for all lanes -> broadcast load) ---
        const float* bx = boxes + (size_t)bn * BOX_DIM;
        bool valid = false;
#pragma unroll
        for (int j = 0; j < BOX_DIM; ++j) valid = valid || (bx[j] != 0.0f);

        float x1 = fminf(fmaxf(bx[0], 0.0f), (float)(Ww - 1));
        float y1 = fminf(fmaxf(bx[1], 0.0f), (float)(Hh - 1));
        float x2 = fminf(fmaxf(bx[2], 0.0f), (float)(Ww - 1));
        float y2 = fminf(fmaxf(bx[3], 0.0f), (float)(Hh - 1));
        // reference ordering exactly (sequential updates)
        x1 = fminf(x1, x2);
        x2 = fmaxf(x1, x2);
        y1 = fminf(y1, y2);
        y2 = fmaxf(y1, y2);

        // wave-uniform ints -> scalar control flow everywhere below
        int x1i = __builtin_amdgcn_readfirstlane((int)x1);
        int x2i = __builtin_amdgcn_readfirstlane((int)x2);
        int y1i = __builtin_amdgcn_readfirstlane((int)y1);
        int y2i = __builtin_amdgcn_readfirstlane((int)y2);
        if (x2i == x1i) x2i = x1i + 1;
        if (y2i == y1i) y2i = y1i + 1;
        const int Lh = y2i - y1i;      // 1..127
        const int Lw = x2i - x1i;      // 1..127
        const int ylast = y2i - 1;

        const float* fp = feat + ((size_t)(b * Cc + c) * Hh) * Ww;

        // --- stage 1: per-lane column maxes; exact-trip flat row walk ---
        for (int x0 = 0; x0 < Lw; x0 += 64) {
            const int xoff = x0 + lane;
            const int xcol = x1i + min(xoff, Lw - 1);   // clamped, coalesced

            float buf[8];                               // ring, static-indexed
#pragma unroll
            for (int j = 0; j < 8; ++j)
                buf[j] = fp[(size_t)(min(y1i + j, ylast) * Ww) + xcol];

            int   p_cur = 0;
            int   e_cur = y1i + (Lh + POOL - 1) / POOL; // e(0)
            float cur   = -INFINITY;
            float prev  = -INFINITY;
            int   y     = y1i;

            const int ngroups = (Lh + 7) >> 3;
            for (int g = 0; g < ngroups; ++g) {
#pragma unroll
                for (int j = 0; j < 8; ++j) {
                    const float v = buf[j];
                    buf[j] = fp[(size_t)(min(y + 8, ylast) * Ww) + xcol];
                    while (y >= e_cur) {                 // uniform, rarely taken
                        colmax[wave][p_cur][xoff] = cur; // flush bin
                        ++p_cur;
                        const int s_new = y1i + (p_cur * Lh) / POOL;
                        cur = (s_new == y - 1) ? prev : -INFINITY; // 1-row overlap
                        e_cur = (p_cur == POOL - 1)
                                    ? 0x7fffffff
                                    : (y1i + ((p_cur + 1) * Lh + POOL - 1) / POOL);
                    }
                    cur  = fmaxf(cur, v);
                    prev = v;
                    ++y;
                }
            }
            // epilogue: flush current bin; trailing bins all start at ylast
            colmax[wave][p_cur][xoff] = cur;
            for (int p = p_cur + 1; p < POOL; ++p)
                colmax[wave][p][xoff] = prev;
        }

        __syncthreads();

        // --- stage 2: 49 lanes reduce x-bins from LDS, write 49 outputs ---
        if (lane < POOL * POOL) {
            const int p = lane / POOL;
            const int q = lane % POOL;
            const int xs = (q * Lw) / POOL;
            const int xe = ((q + 1) * Lw + POOL - 1) / POOL;
            float m = -INFINITY;
            for (int xo = xs; xo < xe; ++xo)
                m = fmaxf(m, colmax[wave][p][xo]);
            if (!valid) m = 0.0f;
            out[((size_t)bn * Cc + c) * (POOL * POOL) + lane] = m;
        }

        __syncthreads();   // protect colmax before next box's stage 1
    }
}

extern "C" void kernel_launch(void* const* d_in, const int* in_sizes, int n_in,
                              void* d_out, int out_size, void* d_ws, size_t ws_size,
                              hipStream_t stream) {
    const float* feat  = (const float*)d_in[0];
    const float* boxes = (const float*)d_in[1];
    float* out = (float*)d_out;

    // x = channel-group (fast dim -> XCD round-robin), y = box-set (4 boxes each)
    dim3 grid(Cc / WAVES, (Bb * Nn) / BN_PER);   // 32 x 64 = 2048 blocks
    roi_pool_kernel<<<grid, 128, 0, stream>>>(feat, boxes, out);
}

// Round 9
// 25.279 us; speedup vs baseline: 1.1817x; 1.1817x over previous
//
#include <hip/hip_runtime.h>

// ROI max-pooling, faithful to the reference (including the buggy min/max
// ordering). feat: [B=4, C=64, H=128, W=128] f32; boxes: [B, N=64, 7] f32
// out: [B, N, C, 7, 7] f32
//
// Round-9: per-wave body identical to round 7 (exact-trip flat row walk,
// buf[8] ring, scalar bin state machine). Regrouped: 512-thread blocks =
// 8 waves = 8 channels (one octet) of ONE box -> 2048 WGs instead of 8192,
// same 16384 waves, same per-wave work, no intra-block imbalance (all waves
// share Lh/Lw). XCD slicing preserved: XCD = blockIdx.x % 8 = channel octet
// -> 2 MB of feat per XCD (L2-resident).

constexpr int Bb = 4, Cc = 64, Hh = 128, Ww = 128, Nn = 64, BOX_DIM = 7;
constexpr int POOL = 7;
constexpr int WAVES = 8;            // channels per block (one octet)
constexpr int PITCH = Ww + 1;       // 129: breaks power-of-2 bank stride

__global__ __launch_bounds__(512) void roi_pool_kernel(
    const float* __restrict__ feat,
    const float* __restrict__ boxes,
    float* __restrict__ out)
{
    __shared__ float colmax[WAVES][POOL][PITCH];   // 28896 B

    const int bn   = blockIdx.y;                   // box index (B*N)
    const int b    = bn >> 6;                      // Nn = 64
    const int wave = threadIdx.x >> 6;
    const int lane = threadIdx.x & 63;
    const int c    = blockIdx.x * WAVES + wave;    // channel (x-dim -> XCD octet)

    // --- box decode (same address for all lanes -> broadcast load) ---
    const float* bx = boxes + (size_t)bn * BOX_DIM;
    bool valid = false;
#pragma unroll
    for (int i = 0; i < BOX_DIM; ++i) valid = valid || (bx[i] != 0.0f);

    float x1 = fminf(fmaxf(bx[0], 0.0f), (float)(Ww - 1));
    float y1 = fminf(fmaxf(bx[1], 0.0f), (float)(Hh - 1));
    float x2 = fminf(fmaxf(bx[2], 0.0f), (float)(Ww - 1));
    float y2 = fminf(fmaxf(bx[3], 0.0f), (float)(Hh - 1));
    // reference ordering exactly (sequential updates)
    x1 = fminf(x1, x2);
    x2 = fmaxf(x1, x2);
    y1 = fminf(y1, y2);
    y2 = fmaxf(y1, y2);

    // wave-uniform ints -> scalar control flow everywhere below
    int x1i = __builtin_amdgcn_readfirstlane((int)x1);
    int x2i = __builtin_amdgcn_readfirstlane((int)x2);
    int y1i = __builtin_amdgcn_readfirstlane((int)y1);
    int y2i = __builtin_amdgcn_readfirstlane((int)y2);
    if (x2i == x1i) x2i = x1i + 1;
    if (y2i == y1i) y2i = y1i + 1;
    const int Lh = y2i - y1i;      // 1..127
    const int Lw = x2i - x1i;      // 1..127
    const int ylast = y2i - 1;

    const float* fp = feat + ((size_t)(b * Cc + c) * Hh) * Ww;

    // --- stage 1: per-lane column maxes; exact-trip flat row walk ---
    for (int x0 = 0; x0 < Lw; x0 += 64) {
        const int xoff = x0 + lane;
        const int xcol = x1i + min(xoff, Lw - 1);   // clamped, coalesced

        float buf[8];                               // ring, statically indexed
#pragma unroll
        for (int j = 0; j < 8; ++j)
            buf[j] = fp[(size_t)(min(y1i + j, ylast) * Ww) + xcol];

        int   p_cur = 0;
        int   e_cur = y1i + (Lh + POOL - 1) / POOL; // e(0)
        float cur   = -INFINITY;
        float prev  = -INFINITY;
        int   y     = y1i;

        const int ngroups = (Lh + 7) >> 3;
        for (int g = 0; g < ngroups; ++g) {
#pragma unroll
            for (int j = 0; j < 8; ++j) {
                const float v = buf[j];
                buf[j] = fp[(size_t)(min(y + 8, ylast) * Ww) + xcol]; // refill
                while (y >= e_cur) {                 // uniform, rarely taken
                    colmax[wave][p_cur][xoff] = cur; // flush bin
                    ++p_cur;
                    const int s_new = y1i + (p_cur * Lh) / POOL;
                    cur = (s_new == y - 1) ? prev : -INFINITY; // 1-row overlap
                    e_cur = (p_cur == POOL - 1)
                                ? 0x7fffffff         // last bin: flush in epilogue
                                : (y1i + ((p_cur + 1) * Lh + POOL - 1) / POOL);
                }
                cur  = fmaxf(cur, v);
                prev = v;
                ++y;
            }
        }
        // epilogue: flush current bin; trailing bins all start at ylast
        colmax[wave][p_cur][xoff] = cur;
        for (int p = p_cur + 1; p < POOL; ++p)
            colmax[wave][p][xoff] = prev;
    }

    __syncthreads();

    // --- stage 2: 49 lanes reduce x-bins from LDS, write 49 outputs ---
    if (lane < POOL * POOL) {
        const int p = lane / POOL;
        const int q = lane % POOL;
        const int xs = (q * Lw) / POOL;
        const int xe = ((q + 1) * Lw + POOL - 1) / POOL;
        float m = -INFINITY;
        for (int xo = xs; xo < xe; ++xo)
            m = fmaxf(m, colmax[wave][p][xo]);
        if (!valid) m = 0.0f;
        out[((size_t)bn * Cc + c) * (POOL * POOL) + lane] = m;
    }
}

extern "C" void kernel_launch(void* const* d_in, const int* in_sizes, int n_in,
                              void* d_out, int out_size, void* d_ws, size_t ws_size,
                              hipStream_t stream) {
    const float* feat  = (const float*)d_in[0];
    const float* boxes = (const float*)d_in[1];
    float* out = (float*)d_out;

    // x = channel-octet (fast dim -> XCD round-robin), y = box
    dim3 grid(Cc / WAVES, Bb * Nn);   // 8 x 256 = 2048 blocks, 8 waves each
    roi_pool_kernel<<<grid, 512, 0, stream>>>(feat, boxes, out);
}